// Round 1
// baseline (101.482 us; speedup 1.0000x reference)
//
#include <hip/hip_runtime.h>
#include <stdint.h>

#define IMG_W 384
#define IMG_H 384
#define IMG_PIX (IMG_W * IMG_H)
#define N_IMG 16            // 8 pred images + 8 target images
#define SENT 0x7fff         // u16 sentinel: no seed in this row
#define BIGI (1 << 28)      // int sentinel for "no seed found"

// ---------------------------------------------------------------------------
// init: zero the accumulator and per-image has_fg flags (ws is poisoned 0xAA
// once and never re-poisoned, so every launch must re-init).
__global__ void k_init(double* acc, int* flags) {
    int t = threadIdx.x;
    if (t == 0) *acc = 0.0;
    if (t < N_IMG) flags[t] = 0;
}

// ---------------------------------------------------------------------------
// nearest set bit distance within a 384-bit mask held as 6 u64 words.
// position p = wp*64 + b. Returns large value if mask empty.
__device__ __forceinline__ int nearest_bit_dist(const unsigned long long m[6],
                                                int wp, int b) {
    const int BIG = 1 << 20;
    int best = BIG;
    // right side (bits >= p), in-word
    unsigned long long t = m[wp] >> b;
    if (t) best = __builtin_ctzll(t);
    // right side, farther words
#pragma unroll
    for (int w = 0; w < 6; ++w) {
        if (w > wp && m[w]) {
            int cand = ((w - wp) << 6) - b + __builtin_ctzll(m[w]);
            best = min(best, cand);
        }
    }
    // left side (bits <= p), in-word
    unsigned long long u = m[wp] << (63 - b);
    if (u) best = min(best, (int)__builtin_clzll(u));
    // left side, farther words
#pragma unroll
    for (int w = 0; w < 6; ++w) {
        if (w < wp && m[w]) {
            int cand = ((wp - w - 1) << 6) + b + 1 + __builtin_clzll(m[w]);
            best = min(best, cand);
        }
    }
    return best;
}

// ---------------------------------------------------------------------------
// Row pass: one wave per row. Builds the row's fg seed mask via __ballot,
// computes per-position 1-D nearest-seed distances (fg and bg) exactly with
// ctz/clz over the 6 wave-uniform mask words, stores packed u16 pair.
__global__ __launch_bounds__(256) void k_rowpass(const float* __restrict__ pred,
                                                 const float* __restrict__ target,
                                                 uint32_t* __restrict__ d1,
                                                 int* __restrict__ flags) {
    int wave = threadIdx.x >> 6;
    int lane = threadIdx.x & 63;
    int row  = blockIdx.x * 4 + wave;        // 0 .. 6143
    int img  = row / IMG_H;                  // 0 .. 15
    int x    = row - img * IMG_H;
    const float* src = (img < 8) ? (pred + img * IMG_PIX)
                                 : (target + (img - 8) * IMG_PIX);
    const float* rp = src + x * IMG_W;

    unsigned long long mf[6], mb[6];
    bool any_fg = false;
#pragma unroll
    for (int j = 0; j < 6; ++j) {
        float v = rp[lane + 64 * j];
        mf[j] = __ballot(v == 1.0f);
        mb[j] = ~mf[j];
        any_fg = any_fg || (mf[j] != 0ull);
    }
    if (any_fg && lane == 0) atomicOr(&flags[img], 1);

    uint32_t* dst = d1 + row * IMG_W;
#pragma unroll
    for (int j = 0; j < 6; ++j) {
        int kf = nearest_bit_dist(mf, j, lane);
        int kb = nearest_bit_dist(mb, j, lane);
        uint32_t ef = (kf > SENT) ? SENT : (uint32_t)kf;
        uint32_t eb = (kb > SENT) ? SENT : (uint32_t)kb;
        dst[lane + 64 * j] = ef | (eb << 16);
    }
}

// ---------------------------------------------------------------------------
// Column pass + fused loss: per pixel, D(x,y) = min_x' d1[x'][y] + (x-x')^2
// via expanding search with early exit (k^2 >= best). Images with no fg are
// skipped wholesale (field is zeroed by the reference's has_fg where()).
__global__ __launch_bounds__(256) void k_colpass(const float* __restrict__ pred,
                                                 const float* __restrict__ target,
                                                 const uint32_t* __restrict__ d1,
                                                 const int* __restrict__ flags,
                                                 double* __restrict__ acc) {
    const int BLOCKS_PER_IMG = IMG_PIX / 256;   // 576
    int img = blockIdx.x / BLOCKS_PER_IMG;
    int pid = (blockIdx.x % BLOCKS_PER_IMG) * 256 + threadIdx.x;
    int x = pid / IMG_W;
    int y = pid - x * IMG_W;

    float contrib = 0.0f;
    if (flags[img]) {
        const uint32_t* d = d1 + img * IMG_PIX;
        uint32_t c = d[pid];
        int kf = (int)(c & 0xffffu), kb = (int)(c >> 16);
        int bf = (kf >= SENT) ? BIGI : kf * kf;
        int bb = (kb >= SENT) ? BIGI : kb * kb;
        int k = 1, kk = 1;
        while ((kk < bf || kk < bb) && k < IMG_H) {
            int xm = x - k, xp = x + k;
            if (xm >= 0) {
                uint32_t cc = d[xm * IMG_W + y];
                int f = (int)(cc & 0xffffu), b2 = (int)(cc >> 16);
                if (f  < SENT) bf = min(bf, f * f + kk);
                if (b2 < SENT) bb = min(bb, b2 * b2 + kk);
            }
            if (xp < IMG_H) {
                uint32_t cc = d[xp * IMG_W + y];
                int f = (int)(cc & 0xffffu), b2 = (int)(cc >> 16);
                if (f  < SENT) bf = min(bf, f * f + kk);
                if (b2 < SENT) bb = min(bb, b2 * b2 + kk);
            }
            ++k;
            kk = k * k;
        }
        float dbf = (bf >= BIGI) ? 1e12f : (float)bf;
        float dbb = (bb >= BIGI) ? 1e12f : (float)bb;
        float dt2 = dbf + dbb;                 // field^2 (one term always 0)
        int off = (img & 7) * IMG_PIX + pid;   // same (b,c,x,y) in pred/target
        float e = pred[off] - target[off];
        contrib = e * e * dt2;
    }

    // block reduction: wave shuffle + LDS, one double atomic per block
    for (int o = 32; o > 0; o >>= 1) contrib += __shfl_down(contrib, o);
    __shared__ float part[4];
    int wv = threadIdx.x >> 6, ln = threadIdx.x & 63;
    if (ln == 0) part[wv] = contrib;
    __syncthreads();
    if (threadIdx.x == 0) {
        float s = part[0] + part[1] + part[2] + part[3];
        if (s != 0.0f) atomicAdd(acc, (double)s);
    }
}

// ---------------------------------------------------------------------------
__global__ void k_final(const double* __restrict__ acc, float* __restrict__ out) {
    out[0] = (float)(*acc * (1.0 / (double)(8 * IMG_PIX)));
}

// ---------------------------------------------------------------------------
extern "C" void kernel_launch(void* const* d_in, const int* in_sizes, int n_in,
                              void* d_out, int out_size, void* d_ws, size_t ws_size,
                              hipStream_t stream) {
    const float* pred   = (const float*)d_in[0];
    const float* target = (const float*)d_in[1];
    char* ws = (char*)d_ws;
    double*   acc   = (double*)ws;              // 8 B
    int*      flags = (int*)(ws + 16);          // 16 ints
    uint32_t* d1    = (uint32_t*)(ws + 128);    // 16*384*384 u32 = 9.44 MB

    k_init   <<<1, 64, 0, stream>>>(acc, flags);
    k_rowpass<<<N_IMG * IMG_H / 4, 256, 0, stream>>>(pred, target, d1, flags);
    k_colpass<<<N_IMG * (IMG_PIX / 256), 256, 0, stream>>>(pred, target, d1, flags, acc);
    k_final  <<<1, 1, 0, stream>>>(acc, (float*)d_out);
}

// Round 2
// 68.668 us; speedup vs baseline: 1.4779x; 1.4779x over previous
//
#include <hip/hip_runtime.h>
#include <stdint.h>

#define IMG_W 384
#define IMG_H 384
#define IMG_PIX (IMG_W * IMG_H)
#define N_IMG 16            // 8 pred images + 8 target images
#define SENT 0x7fff         // u16 sentinel: no seed in this row
#define BIGI (1 << 28)      // int sentinel for "no seed found"
#define COL_BLOCKS (N_IMG * (IMG_PIX / 256))   // 9216

// ---------------------------------------------------------------------------
// init: zero per-image has_fg flags (ws is poisoned 0xAA once, never
// re-poisoned, so every launch must re-init everything it reads).
__global__ void k_init(int* flags) {
    int t = threadIdx.x;
    if (t < N_IMG) flags[t] = 0;
}

// ---------------------------------------------------------------------------
// nearest set bit distance within a 384-bit mask held as 6 u64 words.
// position p = wp*64 + b. Returns large value if mask empty.
__device__ __forceinline__ int nearest_bit_dist(const unsigned long long m[6],
                                                int wp, int b) {
    const int BIG = 1 << 20;
    int best = BIG;
    unsigned long long t = m[wp] >> b;
    if (t) best = __builtin_ctzll(t);
#pragma unroll
    for (int w = 0; w < 6; ++w) {
        if (w > wp && m[w]) {
            int cand = ((w - wp) << 6) - b + __builtin_ctzll(m[w]);
            best = min(best, cand);
        }
    }
    unsigned long long u = m[wp] << (63 - b);
    if (u) best = min(best, (int)__builtin_clzll(u));
#pragma unroll
    for (int w = 0; w < 6; ++w) {
        if (w < wp && m[w]) {
            int cand = ((wp - w - 1) << 6) + b + 1 + __builtin_clzll(m[w]);
            best = min(best, cand);
        }
    }
    return best;
}

// ---------------------------------------------------------------------------
// Row pass: one wave per row. Builds the row's fg seed mask via __ballot,
// computes per-position 1-D nearest-seed distances (fg and bg) exactly with
// ctz/clz over the 6 wave-uniform mask words, stores packed u16 pair.
__global__ __launch_bounds__(256) void k_rowpass(const float* __restrict__ pred,
                                                 const float* __restrict__ target,
                                                 uint32_t* __restrict__ d1,
                                                 int* __restrict__ flags) {
    int wave = threadIdx.x >> 6;
    int lane = threadIdx.x & 63;
    int row  = blockIdx.x * 4 + wave;        // 0 .. 6143
    int img  = row / IMG_H;                  // 0 .. 15
    int x    = row - img * IMG_H;
    const float* src = (img < 8) ? (pred + img * IMG_PIX)
                                 : (target + (img - 8) * IMG_PIX);
    const float* rp = src + x * IMG_W;

    unsigned long long mf[6], mb[6];
    bool any_fg = false;
#pragma unroll
    for (int j = 0; j < 6; ++j) {
        float v = rp[lane + 64 * j];
        mf[j] = __ballot(v == 1.0f);
        mb[j] = ~mf[j];
        any_fg = any_fg || (mf[j] != 0ull);
    }
    if (any_fg && lane == 0) atomicOr(&flags[img], 1);

    uint32_t* dst = d1 + row * IMG_W;
#pragma unroll
    for (int j = 0; j < 6; ++j) {
        int kf = nearest_bit_dist(mf, j, lane);
        int kb = nearest_bit_dist(mb, j, lane);
        uint32_t ef = (kf > SENT) ? SENT : (uint32_t)kf;
        uint32_t eb = (kb > SENT) ? SENT : (uint32_t)kb;
        dst[lane + 64 * j] = ef | (eb << 16);
    }
}

// ---------------------------------------------------------------------------
// Column pass + fused loss: per pixel, D(x,y) = min_x' d1[x'][y] + (x-x')^2
// via expanding search with early exit (k^2 >= best). Images with no fg are
// skipped wholesale. One partial-sum write per block (no global atomic —
// 9216 same-address f64 atomics were 13 ns each = the whole 61 µs).
__global__ __launch_bounds__(256) void k_colpass(const float* __restrict__ pred,
                                                 const float* __restrict__ target,
                                                 const uint32_t* __restrict__ d1,
                                                 const int* __restrict__ flags,
                                                 float* __restrict__ partials) {
    const int BLOCKS_PER_IMG = IMG_PIX / 256;   // 576
    int img = blockIdx.x / BLOCKS_PER_IMG;
    int pid = (blockIdx.x % BLOCKS_PER_IMG) * 256 + threadIdx.x;
    int x = pid / IMG_W;
    int y = pid - x * IMG_W;

    float contrib = 0.0f;
    if (flags[img]) {
        const uint32_t* d = d1 + img * IMG_PIX;
        uint32_t c = d[pid];
        int kf = (int)(c & 0xffffu), kb = (int)(c >> 16);
        int bf = (kf >= SENT) ? BIGI : kf * kf;
        int bb = (kb >= SENT) ? BIGI : kb * kb;
        int k = 1, kk = 1;
        while ((kk < bf || kk < bb) && k < IMG_H) {
            int xm = x - k, xp = x + k;
            if (xm >= 0) {
                uint32_t cc = d[xm * IMG_W + y];
                int f = (int)(cc & 0xffffu), b2 = (int)(cc >> 16);
                if (f  < SENT) bf = min(bf, f * f + kk);
                if (b2 < SENT) bb = min(bb, b2 * b2 + kk);
            }
            if (xp < IMG_H) {
                uint32_t cc = d[xp * IMG_W + y];
                int f = (int)(cc & 0xffffu), b2 = (int)(cc >> 16);
                if (f  < SENT) bf = min(bf, f * f + kk);
                if (b2 < SENT) bb = min(bb, b2 * b2 + kk);
            }
            ++k;
            kk = k * k;
        }
        float dbf = (bf >= BIGI) ? 1e12f : (float)bf;
        float dbb = (bb >= BIGI) ? 1e12f : (float)bb;
        float dt2 = dbf + dbb;                 // field^2 (one term always 0)
        int off = (img & 7) * IMG_PIX + pid;   // same (b,c,x,y) in pred/target
        float e = pred[off] - target[off];
        contrib = e * e * dt2;
    }

    // block reduction: wave shuffle + LDS, one partial write per block
    for (int o = 32; o > 0; o >>= 1) contrib += __shfl_down(contrib, o);
    __shared__ float part[4];
    int wv = threadIdx.x >> 6, ln = threadIdx.x & 63;
    if (ln == 0) part[wv] = contrib;
    __syncthreads();
    if (threadIdx.x == 0)
        partials[blockIdx.x] = part[0] + part[1] + part[2] + part[3];
}

// ---------------------------------------------------------------------------
// final: one block reduces the 9216 per-block partials in double.
__global__ __launch_bounds__(256) void k_final(const float* __restrict__ partials,
                                               float* __restrict__ out) {
    double s = 0.0;
    for (int i = threadIdx.x; i < COL_BLOCKS; i += 256)
        s += (double)partials[i];
    for (int o = 32; o > 0; o >>= 1) s += __shfl_down(s, o);
    __shared__ double part[4];
    int wv = threadIdx.x >> 6, ln = threadIdx.x & 63;
    if (ln == 0) part[wv] = s;
    __syncthreads();
    if (threadIdx.x == 0)
        out[0] = (float)((part[0] + part[1] + part[2] + part[3]) *
                         (1.0 / (double)(8 * IMG_PIX)));
}

// ---------------------------------------------------------------------------
extern "C" void kernel_launch(void* const* d_in, const int* in_sizes, int n_in,
                              void* d_out, int out_size, void* d_ws, size_t ws_size,
                              hipStream_t stream) {
    const float* pred   = (const float*)d_in[0];
    const float* target = (const float*)d_in[1];
    char* ws = (char*)d_ws;
    int*      flags    = (int*)ws;                  // 16 ints
    float*    partials = (float*)(ws + 128);        // 9216 floats = 36 KB
    uint32_t* d1       = (uint32_t*)(ws + 128 + 4 * COL_BLOCKS + 64);

    k_init   <<<1, 64, 0, stream>>>(flags);
    k_rowpass<<<N_IMG * IMG_H / 4, 256, 0, stream>>>(pred, target, d1, flags);
    k_colpass<<<COL_BLOCKS, 256, 0, stream>>>(pred, target, d1, flags, partials);
    k_final  <<<1, 256, 0, stream>>>(partials, (float*)d_out);
}

// Round 3
// 38.984 us; speedup vs baseline: 2.6032x; 1.7614x over previous
//
#include <hip/hip_runtime.h>
#include <stdint.h>

#define IMG_W 384
#define IMG_H 384
#define IMG_PIX (IMG_W * IMG_H)
#define N_IMG 16            // 8 pred images + 8 target images
#define SENT 0x7fff         // u16 sentinel: no seed in this row
#define BIGI (1 << 28)      // int sentinel for "no seed found"
#define COL_BLOCKS (N_IMG * (IMG_PIX / 256))   // 9216
#define FLAG_STRIDE 32      // 128 B between flags: no shared cacheline

// ---------------------------------------------------------------------------
// init: zero per-image has_fg flags (ws is poisoned 0xAA once, never
// re-poisoned, so every launch must re-init everything it reads).
__global__ void k_init(int* flags) {
    int t = threadIdx.x;
    if (t < N_IMG * FLAG_STRIDE) flags[t] = 0;
}

// ---------------------------------------------------------------------------
// nearest set bit distance within a 384-bit mask held as 6 u64 words.
// position p = wp*64 + b. Returns large value if mask empty.
__device__ __forceinline__ int nearest_bit_dist(const unsigned long long m[6],
                                                int wp, int b) {
    const int BIG = 1 << 20;
    int best = BIG;
    unsigned long long t = m[wp] >> b;
    if (t) best = __builtin_ctzll(t);
#pragma unroll
    for (int w = 0; w < 6; ++w) {
        if (w > wp && m[w]) {
            int cand = ((w - wp) << 6) - b + __builtin_ctzll(m[w]);
            best = min(best, cand);
        }
    }
    unsigned long long u = m[wp] << (63 - b);
    if (u) best = min(best, (int)__builtin_clzll(u));
#pragma unroll
    for (int w = 0; w < 6; ++w) {
        if (w < wp && m[w]) {
            int cand = ((wp - w - 1) << 6) + b + 1 + __builtin_clzll(m[w]);
            best = min(best, cand);
        }
    }
    return best;
}

// ---------------------------------------------------------------------------
// Row pass: one wave per row. Builds the row's fg seed mask via __ballot,
// computes per-position 1-D nearest-seed distances (fg and bg) exactly with
// ctz/clz over the 6 wave-uniform mask words, stores packed u16 pair.
// has_fg flag: PLAIN racing store of 1 (idempotent) — the previous atomicOr
// to one shared cacheline serialized 3072 RMWs = the entire 41 us runtime.
__global__ __launch_bounds__(256) void k_rowpass(const float* __restrict__ pred,
                                                 const float* __restrict__ target,
                                                 uint32_t* __restrict__ d1,
                                                 int* __restrict__ flags) {
    int wave = threadIdx.x >> 6;
    int lane = threadIdx.x & 63;
    int row  = blockIdx.x * 4 + wave;        // 0 .. 6143
    int img  = row / IMG_H;                  // 0 .. 15
    int x    = row - img * IMG_H;
    const float* src = (img < 8) ? (pred + img * IMG_PIX)
                                 : (target + (img - 8) * IMG_PIX);
    const float* rp = src + x * IMG_W;

    unsigned long long mf[6], mb[6];
    bool any_fg = false;
#pragma unroll
    for (int j = 0; j < 6; ++j) {
        float v = rp[lane + 64 * j];
        mf[j] = __ballot(v == 1.0f);
        mb[j] = ~mf[j];
        any_fg = any_fg || (mf[j] != 0ull);
    }
    if (any_fg && lane == 0) flags[img * FLAG_STRIDE] = 1;   // benign race

    uint32_t* dst = d1 + row * IMG_W;
#pragma unroll
    for (int j = 0; j < 6; ++j) {
        int kf = nearest_bit_dist(mf, j, lane);
        int kb = nearest_bit_dist(mb, j, lane);
        uint32_t ef = (kf > SENT) ? SENT : (uint32_t)kf;
        uint32_t eb = (kb > SENT) ? SENT : (uint32_t)kb;
        dst[lane + 64 * j] = ef | (eb << 16);
    }
}

// ---------------------------------------------------------------------------
// Column pass + fused loss: per pixel, D(x,y) = min_x' d1[x'][y] + (x-x')^2
// via expanding search with early exit (k^2 >= best). Images with no fg are
// skipped wholesale. One partial-sum write per block.
__global__ __launch_bounds__(256) void k_colpass(const float* __restrict__ pred,
                                                 const float* __restrict__ target,
                                                 const uint32_t* __restrict__ d1,
                                                 const int* __restrict__ flags,
                                                 float* __restrict__ partials) {
    const int BLOCKS_PER_IMG = IMG_PIX / 256;   // 576
    int img = blockIdx.x / BLOCKS_PER_IMG;
    int pid = (blockIdx.x % BLOCKS_PER_IMG) * 256 + threadIdx.x;
    int x = pid / IMG_W;
    int y = pid - x * IMG_W;

    float contrib = 0.0f;
    if (flags[img * FLAG_STRIDE]) {
        // issue the (independent) error-term loads before the search chain
        int off = (img & 7) * IMG_PIX + pid;   // same (b,c,x,y) in pred/target
        float pv = pred[off];
        float tv = target[off];

        const uint32_t* d = d1 + img * IMG_PIX;
        uint32_t c = d[pid];
        int kf = (int)(c & 0xffffu), kb = (int)(c >> 16);
        int bf = (kf >= SENT) ? BIGI : kf * kf;
        int bb = (kb >= SENT) ? BIGI : kb * kb;
        int k = 1, kk = 1;
        while ((kk < bf || kk < bb) && k < IMG_H) {
            int xm = x - k, xp = x + k;
            if (xm >= 0) {
                uint32_t cc = d[xm * IMG_W + y];
                int f = (int)(cc & 0xffffu), b2 = (int)(cc >> 16);
                if (f  < SENT) bf = min(bf, f * f + kk);
                if (b2 < SENT) bb = min(bb, b2 * b2 + kk);
            }
            if (xp < IMG_H) {
                uint32_t cc = d[xp * IMG_W + y];
                int f = (int)(cc & 0xffffu), b2 = (int)(cc >> 16);
                if (f  < SENT) bf = min(bf, f * f + kk);
                if (b2 < SENT) bb = min(bb, b2 * b2 + kk);
            }
            ++k;
            kk = k * k;
        }
        float dbf = (bf >= BIGI) ? 1e12f : (float)bf;
        float dbb = (bb >= BIGI) ? 1e12f : (float)bb;
        float dt2 = dbf + dbb;                 // field^2 (one term always 0)
        float e = pv - tv;
        contrib = e * e * dt2;
    }

    // block reduction: wave shuffle + LDS, one partial write per block
    for (int o = 32; o > 0; o >>= 1) contrib += __shfl_down(contrib, o);
    __shared__ float part[4];
    int wv = threadIdx.x >> 6, ln = threadIdx.x & 63;
    if (ln == 0) part[wv] = contrib;
    __syncthreads();
    if (threadIdx.x == 0)
        partials[blockIdx.x] = part[0] + part[1] + part[2] + part[3];
}

// ---------------------------------------------------------------------------
// final: one block reduces the 9216 per-block partials in double.
__global__ __launch_bounds__(256) void k_final(const float* __restrict__ partials,
                                               float* __restrict__ out) {
    double s = 0.0;
    for (int i = threadIdx.x; i < COL_BLOCKS; i += 256)
        s += (double)partials[i];
    for (int o = 32; o > 0; o >>= 1) s += __shfl_down(s, o);
    __shared__ double part[4];
    int wv = threadIdx.x >> 6, ln = threadIdx.x & 63;
    if (ln == 0) part[wv] = s;
    __syncthreads();
    if (threadIdx.x == 0)
        out[0] = (float)((part[0] + part[1] + part[2] + part[3]) *
                         (1.0 / (double)(8 * IMG_PIX)));
}

// ---------------------------------------------------------------------------
extern "C" void kernel_launch(void* const* d_in, const int* in_sizes, int n_in,
                              void* d_out, int out_size, void* d_ws, size_t ws_size,
                              hipStream_t stream) {
    const float* pred   = (const float*)d_in[0];
    const float* target = (const float*)d_in[1];
    char* ws = (char*)d_ws;
    int*      flags    = (int*)ws;                  // 16 * 128 B
    float*    partials = (float*)(ws + 4096);       // 9216 floats = 36 KB
    uint32_t* d1       = (uint32_t*)(ws + 4096 + 4 * COL_BLOCKS + 64);

    k_init   <<<1, N_IMG * FLAG_STRIDE, 0, stream>>>(flags);
    k_rowpass<<<N_IMG * IMG_H / 4, 256, 0, stream>>>(pred, target, d1, flags);
    k_colpass<<<COL_BLOCKS, 256, 0, stream>>>(pred, target, d1, flags, partials);
    k_final  <<<1, 256, 0, stream>>>(partials, (float*)d_out);
}